// Round 12
// baseline (63.615 us; speedup 1.0000x reference)
//
#include <hip/hip_runtime.h>

// SKAttention fused, MI355X — 3-launch pipeline: means / (z+diag) / outf.
// x,x1 (128,512,16,16) f32; fc_w (32,512); fc_b (32); fcs_w (2,512,32); fcs_b (2,512).
// Out: 2 x (128,512,12,16) f32 concat.
//
// attn0 = sigmoid(l0-l1). Group 0 dropped -> rows 0..3 dead. p = 4g+j, g in 1..3.
// out1[b,ch,4(g-1)+h,4j+w] = attn0(g,j,b,ch)*x[b,ch,4g+h,4j+w] + x[4g+j,ch,4g+h,4j+w]
// out2 same with x1, 1-attn0.
//
// Ledger of PROVEN-fast pieces: means r2-structure ~17us, out-stream ~13us
// (NT, r5/r9), diag ~2us. Every round that attached extra work to the means
// kernel (r9 shfl: +40us, r11 LDS-dot: +~25us) poisoned it. So: means is a
// byte-level r2 clone; Z matvec is a separate tiny kernel (fc_w transposed
// IN LDS, no global round-trip, no gathers); diag folded into the same
// launch via block-role branch. outf uses NT stores: out is never re-read,
// and bypassing L3 keeps x/x1 resident so next-iteration means reads hit L3.

#define BS 128
#define C  512
#define D  32

typedef float f32x4 __attribute__((ext_vector_type(4)));

// K1: patch means of (x+x1) -> S[g1][b][j*C+ch]. EXACT r2 structure.
__global__ __launch_bounds__(256) void skatt_means(
    const float* __restrict__ x, const float* __restrict__ x1,
    float* __restrict__ S)
{
    const int g = blockIdx.x + 1;
    const int b = blockIdx.y;
    const int q = blockIdx.z;
    const int t = threadIdx.x;
    const int j  = t & 3;
    const int cl = t >> 2;

    const size_t base = (size_t)b * (C * 256);
    float* Sgb = S + ((size_t)(g - 1) * BS + b) * (4 * C);

    #pragma unroll
    for (int i = 0; i < 2; ++i) {
        const int ch = q * 128 + cl + i * 64;
        const float* px = x  + base + ch * 256 + (4 * g) * 16 + j * 4;
        const float* p1 = x1 + base + ch * 256 + (4 * g) * 16 + j * 4;
        float s = 0.f;
        #pragma unroll
        for (int h = 0; h < 4; ++h) {
            float4 a  = *(const float4*)(px + h * 16);
            float4 c2 = *(const float4*)(p1 + h * 16);
            s += (a.x + c2.x) + (a.y + c2.y) + (a.z + c2.z) + (a.w + c2.w);
        }
        Sgb[j * C + ch] = s * (1.0f / 16.0f);
    }
}

// K2 "mid": blocks 0..383 compute Z; blocks 384..575 copy diag extras.
// Z[((g1*BS+b)*4+j)*32+d] = fc_b[d] + sum_c S[g1][b][j*C+c] * fc_w[d][c]
// fc_w is transposed inside LDS (coalesced global reads), so the dot has
// zero gathered global loads and conflict-free LDS reads.
__global__ __launch_bounds__(256) void skatt_mid(
    const float* __restrict__ x, const float* __restrict__ x1,
    const float* __restrict__ S, const float* __restrict__ fc_w,
    const float* __restrict__ fc_b,
    float* __restrict__ E, float* __restrict__ Z)
{
    __shared__ float s_w[C][33];     // [c][d] transposed fc_w, 67.6 KB
    __shared__ float s_S[4 * C];     // [j][c] means slice, 8 KB

    const int blk = blockIdx.x;
    const int t = threadIdx.x;

    if (blk < 384) {
        const int g1 = blk >> 7, b = blk & 127;

        // stage fc_w transposed: thread (d, c-chunk) reads 16 float4 of row d
        {
            const int d  = t >> 3;
            const int c0 = (t & 7) * 64;
            const float4* wr = (const float4*)(fc_w + d * C + c0);
            #pragma unroll
            for (int k = 0; k < 16; ++k) {
                float4 v = wr[k];
                const int c = c0 + k * 4;
                s_w[c + 0][d] = v.x;
                s_w[c + 1][d] = v.y;
                s_w[c + 2][d] = v.z;
                s_w[c + 3][d] = v.w;
            }
        }
        // stage S slice (2 KB contiguous)
        {
            const float4* Ss = (const float4*)(S + ((size_t)g1 * BS + b) * (4 * C));
            ((float4*)s_S)[t]       = Ss[t];
            ((float4*)s_S)[t + 256] = Ss[t + 256];
        }
        __syncthreads();

        if (t < 128) {
            const int j = t >> 5, d = t & 31;
            const float* sr = s_S + j * C;
            float a0 = 0.f, a1 = 0.f, a2 = 0.f, a3 = 0.f;
            #pragma unroll 8
            for (int c = 0; c < C; c += 4) {
                a0 += sr[c + 0] * s_w[c + 0][d];
                a1 += sr[c + 1] * s_w[c + 1][d];
                a2 += sr[c + 2] * s_w[c + 2][d];
                a3 += sr[c + 3] * s_w[c + 3][d];
            }
            Z[((size_t)(g1 * BS + b) * 4 + j) * 32 + d] =
                (a0 + a1) + (a2 + a3) + fc_b[d];
        }
    } else {
        // diag role: E[src][ch*192 + (g-1)*64 + h*16 + j*4 + w] = src[4g+j][ch][4g+h][4j+w]
        const int blk2 = blk - 384;           // 0..191
        const int src  = blk2 >= 96;
        const int bb   = src ? blk2 - 96 : blk2;
        const float* in = src ? x1 : x;
        float* Eo = E + (size_t)src * (C * 192);

        const int flat = bb * 256 + t;        // 0..24575 float4
        const int ch  = flat / 48;
        const int rem = flat - ch * 48;
        const int g   = (rem >> 4) + 1;
        const int h   = (rem >> 2) & 3;
        const int j   = rem & 3;

        const size_t src_ofs = (size_t)(4 * g + j) * (C * 256) + ch * 256 + (4 * g + h) * 16 + 4 * j;
        float4 v = *(const float4*)(in + src_ofs);
        *(float4*)(Eo + ch * 192 + rem * 4) = v;
    }
}

// K3: fused attn + streaming output (NT stores). Grid (16 ch-chunks, 128 b).
__global__ __launch_bounds__(256) void skatt_outf(
    const float* __restrict__ x, const float* __restrict__ x1,
    const float* __restrict__ E, const float* __restrict__ Z,
    const float* __restrict__ fcs_w, const float* __restrict__ fcs_b,
    float* __restrict__ out)
{
    const int q = blockIdx.x;      // 32-ch chunk
    const int b = blockIdx.y;
    const int t = threadIdx.x;
    const int ch0 = q * 32;

    __shared__ float s_z[3][128];    // [g1][j*32+d]
    __shared__ float s_wt[32][33];   // [d][ch_l], padded
    __shared__ float s_bd[32];
    __shared__ float s_A[32][12];    // [ch_l][g1*4+j]

    // Z slice: 96 threads, one f32x4 each
    if (t < 96) {
        const int g1 = t >> 5, j = (t >> 3) & 3, d4 = t & 7;
        f32x4 v = ((const f32x4*)Z)[(size_t)(g1 * BS + b) * 32 + j * 8 + d4];
        *(f32x4*)(&s_z[g1][j * 32 + d4 * 4]) = v;
    }
    // Wd = fcs_w0 - fcs_w1 transposed into LDS (all 256 threads)
    {
        const f32x4* w04 = (const f32x4*)(fcs_w + (size_t)ch0 * D);
        const f32x4* w14 = (const f32x4*)(fcs_w + (size_t)C * D + (size_t)ch0 * D);
        f32x4 a  = w04[t];
        f32x4 bb = w14[t];
        const int ch = t >> 3, d0 = (t & 7) * 4;
        s_wt[d0 + 0][ch] = a.x - bb.x;
        s_wt[d0 + 1][ch] = a.y - bb.y;
        s_wt[d0 + 2][ch] = a.z - bb.z;
        s_wt[d0 + 3][ch] = a.w - bb.w;
    }
    if (t < 32) s_bd[t] = fcs_b[ch0 + t] - fcs_b[C + ch0 + t];
    __syncthreads();

    // attn: 32ch x 12 (g,j) sigmoids (k = t>>5 handles p=k and p=k+8)
    {
        const int ch_l = t & 31, k = t >> 5;
        float wd[D];
        #pragma unroll
        for (int d = 0; d < D; ++d) wd[d] = s_wt[d][ch_l];
        const float bdv = s_bd[ch_l];

        {
            const int g1 = k >> 2, j = k & 3;
            float acc = bdv;
            #pragma unroll
            for (int d = 0; d < D; ++d) acc += s_z[g1][j * 32 + d] * wd[d];
            s_A[ch_l][k] = 1.0f / (1.0f + __expf(-acc));
        }
        if (k < 4) {
            const int p = k + 8;
            const int g1 = p >> 2, j = p & 3;
            float acc = bdv;
            #pragma unroll
            for (int d = 0; d < D; ++d) acc += s_z[g1][j * 32 + d] * wd[d];
            s_A[ch_l][p] = 1.0f / (1.0f + __expf(-acc));
        }
    }
    __syncthreads();

    // streaming elementwise output, nontemporal float4 stores
    const size_t xbase = (size_t)b * (C * 256);
    const size_t obase = (size_t)b * (C * 192);
    const size_t out2_off = (size_t)BS * C * 192;
    const float* E1 = E;
    const float* E2 = E + (size_t)C * 192;

    #pragma unroll
    for (int i = 0; i < 6; ++i) {
        const int v    = t + i * 256;        // 0..1535 float4 index
        const int ch_l = v / 48;             // 0..31
        const int rem  = v - ch_l * 48;      // g1*16 + h*4 + j
        const int ch   = ch0 + ch_l;
        const int j    = rem & 3;
        const int g1   = rem >> 4;

        const float at0 = s_A[ch_l][g1 * 4 + j];
        const float at1 = 1.0f - at0;

        const size_t xofs = xbase + ch * 256 + 64 + rem * 4;
        float4 a  = *(const float4*)(x  + xofs);
        float4 c2 = *(const float4*)(x1 + xofs);
        const size_t eofs = (size_t)ch * 192 + rem * 4;
        float4 e1 = *(const float4*)(E1 + eofs);
        float4 e2 = *(const float4*)(E2 + eofs);

        f32x4 r1, r2;
        r1.x = at0 * a.x + e1.x;   r2.x = at1 * c2.x + e2.x;
        r1.y = at0 * a.y + e1.y;   r2.y = at1 * c2.y + e2.y;
        r1.z = at0 * a.z + e1.z;   r2.z = at1 * c2.z + e2.z;
        r1.w = at0 * a.w + e1.w;   r2.w = at1 * c2.w + e2.w;

        const size_t oofs = obase + ch * 192 + rem * 4;
        __builtin_nontemporal_store(r1, (f32x4*)(out + oofs));
        __builtin_nontemporal_store(r2, (f32x4*)(out + out2_off + oofs));
    }
}

extern "C" void kernel_launch(void* const* d_in, const int* in_sizes, int n_in,
                              void* d_out, int out_size, void* d_ws, size_t ws_size,
                              hipStream_t stream) {
    const float* x     = (const float*)d_in[0];
    const float* x1    = (const float*)d_in[1];
    const float* fc_w  = (const float*)d_in[2];
    const float* fc_b  = (const float*)d_in[3];
    const float* fcs_w = (const float*)d_in[4];
    const float* fcs_b = (const float*)d_in[5];
    float* out = (float*)d_out;

    float* S = (float*)d_ws;            // 3*128*4*512 = 786432 f
    float* E = S + 786432;              // 196608 f
    float* Z = E + 196608;              // 49152 f

    skatt_means<<<dim3(3, BS, 4), 256, 0, stream>>>(x, x1, S);
    skatt_mid  <<<576,            256, 0, stream>>>(x, x1, S, fc_w, fc_b, E, Z);
    skatt_outf <<<dim3(16, BS),   256, 0, stream>>>(x, x1, E, Z, fcs_w, fcs_b, out);
}

// Round 13
// 53.716 us; speedup vs baseline: 1.1843x; 1.1843x over previous
//
#include <hip/hip_runtime.h>

// SKAttention fused, MI355X — 2-launch pipeline: (means+z+diag) / outf.
// x,x1 (128,512,16,16) f32; fc_w (32,512); fc_b (32); fcs_w (2,512,32); fcs_b (2,512).
// Out: 2 x (128,512,12,16) f32 concat.
//
// attn0 = sigmoid(l0-l1). Group 0 dropped -> rows 0..3 dead. p = 4g+j, g in 1..3.
// out1[b,ch,4(g-1)+h,4j+w] = attn0(g,j,b,ch)*x[b,ch,4g+h,4j+w] + x[4g+j,ch,4g+h,4j+w]
// out2 same with x1, 1-attn0.
//
// Ledger (r10-r12 consistent): meanz~22, diag~2, outf(plain)~33 (moves ~196MB,
// near floor), NT stores cost +5us twice (r9/r10, r11/r12) -> plain stores.
// This round: meanz phase-B on all 256 threads (split-c + LDS combine) and
// diag folded into the meanz launch as a block-role (z==4). outf unchanged.

#define BS 128
#define C  512
#define D  32

typedef float f32x4 __attribute__((ext_vector_type(4)));

// K1: z in 0..3 -> patch means + partial Z dot for 128-ch chunk q=z.
//     z == 4   -> diag-extras copy role (192 active blocks).
// P[((g1*BS+b)*4 + j)*128 + q*32 + d] = sum_{c in q-chunk} mean[j][c] * fc_w[d][c]
__global__ __launch_bounds__(256) void skatt_meanz(
    const float* __restrict__ x, const float* __restrict__ x1,
    const float* __restrict__ fc_w,
    float* __restrict__ P, float* __restrict__ E)
{
    const int t = threadIdx.x;

    if (blockIdx.z == 4) {
        // ---- diag role ----
        const int flat_b = blockIdx.x * BS + blockIdx.y;   // 0..383
        if (flat_b >= 192) return;
        const int src = flat_b >= 96;
        const int bb  = src ? flat_b - 96 : flat_b;
        const float* in = src ? x1 : x;
        float* Eo = E + (size_t)src * (C * 192);

        const int flat = bb * 256 + t;        // 0..24575 float4
        const int ch  = flat / 48;
        const int rem = flat - ch * 48;
        const int g   = (rem >> 4) + 1;
        const int h   = (rem >> 2) & 3;
        const int j   = rem & 3;

        const size_t src_ofs = (size_t)(4 * g + j) * (C * 256) + ch * 256 + (4 * g + h) * 16 + 4 * j;
        float4 v = *(const float4*)(in + src_ofs);
        *(float4*)(Eo + ch * 192 + rem * 4) = v;
        return;
    }

    const int g = blockIdx.x + 1;
    const int b = blockIdx.y;
    const int q = blockIdx.z;

    __shared__ float s_s[128][4];    // [c_local][j] means (2-way writes = free)
    __shared__ float s_w[128][33];   // [c_local][d] fc_w slice, padded
    __shared__ float s_p[4][2][32];  // [j][half][d] partial dots

    // phase A: streaming means of (x+x1)
    {
        const int j  = t & 3;
        const int cl = t >> 2;   // 0..63
        const size_t base = (size_t)b * (C * 256);
        #pragma unroll
        for (int i = 0; i < 2; ++i) {
            const int ch = q * 128 + cl + i * 64;
            const float* px = x  + base + ch * 256 + (4 * g) * 16 + j * 4;
            const float* p1 = x1 + base + ch * 256 + (4 * g) * 16 + j * 4;
            float s = 0.f;
            #pragma unroll
            for (int h = 0; h < 4; ++h) {
                float4 a  = *(const float4*)(px + h * 16);
                float4 c2 = *(const float4*)(p1 + h * 16);
                s += (a.x + c2.x) + (a.y + c2.y) + (a.z + c2.z) + (a.w + c2.w);
            }
            s_s[cl + i * 64][j] = s * (1.0f / 16.0f);
        }
    }

    // phase A2: stage fc_w q-slice transposed (coalesced global reads)
    {
        const int d  = t >> 3;          // 0..31
        const int c4 = t & 7;           // 0..7
        const float* wsrc = fc_w + d * C + q * 128 + c4 * 16;
        #pragma unroll
        for (int k = 0; k < 4; ++k) {
            float4 v = *(const float4*)(wsrc + k * 4);
            const int c = c4 * 16 + k * 4;
            s_w[c + 0][d] = v.x;
            s_w[c + 1][d] = v.y;
            s_w[c + 2][d] = v.z;
            s_w[c + 3][d] = v.w;
        }
    }
    __syncthreads();

    // phase B: all 256 threads: (j, d, c-half) partial dots
    {
        const int j    = t >> 6;         // 0..3
        const int d    = t & 31;
        const int half = (t >> 5) & 1;
        const int c0   = half * 64;
        float a0 = 0.f, a1 = 0.f, a2 = 0.f, a3 = 0.f;
        #pragma unroll 8
        for (int c = c0; c < c0 + 64; c += 4) {
            a0 += s_s[c + 0][j] * s_w[c + 0][d];
            a1 += s_s[c + 1][j] * s_w[c + 1][d];
            a2 += s_s[c + 2][j] * s_w[c + 2][d];
            a3 += s_s[c + 3][j] * s_w[c + 3][d];
        }
        s_p[j][half][d] = (a0 + a1) + (a2 + a3);
    }
    __syncthreads();

    if (t < 128) {
        const int j = t >> 5, d = t & 31;
        P[((size_t)((g - 1) * BS + b) * 4 + j) * 128 + q * 32 + d] =
            s_p[j][0][d] + s_p[j][1][d];
    }
}

// K2: fused attn + streaming output (plain stores). Grid (16 ch-chunks, 128 b).
__global__ __launch_bounds__(256) void skatt_outf(
    const float* __restrict__ x, const float* __restrict__ x1,
    const float* __restrict__ E, const float* __restrict__ P,
    const float* __restrict__ fc_b,
    const float* __restrict__ fcs_w, const float* __restrict__ fcs_b,
    float* __restrict__ out)
{
    const int q = blockIdx.x;      // 32-ch chunk
    const int b = blockIdx.y;
    const int t = threadIdx.x;
    const int ch0 = q * 32;

    __shared__ float s_z[3][128];    // [g1][j*32+d]
    __shared__ float s_wt[32][33];   // [d][ch_l], padded
    __shared__ float s_bd[32];
    __shared__ float s_A[32][12];    // [ch_l][g1*4+j]

    // Z = sum_q P + fc_b  (96 threads: g1 x j x d4)
    if (t < 96) {
        const int g1 = t >> 5, j = (t >> 3) & 3, d4 = t & 7;
        const f32x4* P4 = (const f32x4*)P;
        const size_t base4 = (size_t)(g1 * BS + b) * 128;
        f32x4 acc = ((const f32x4*)fc_b)[d4];
        #pragma unroll
        for (int qq = 0; qq < 4; ++qq) {
            f32x4 pv = P4[base4 + j * 32 + qq * 8 + d4];
            acc.x += pv.x; acc.y += pv.y; acc.z += pv.z; acc.w += pv.w;
        }
        *(f32x4*)(&s_z[g1][j * 32 + d4 * 4]) = acc;
    }
    // Wd = fcs_w0 - fcs_w1 transposed into LDS (all 256 threads)
    {
        const f32x4* w04 = (const f32x4*)(fcs_w + (size_t)ch0 * D);
        const f32x4* w14 = (const f32x4*)(fcs_w + (size_t)C * D + (size_t)ch0 * D);
        f32x4 a  = w04[t];
        f32x4 bb = w14[t];
        const int ch = t >> 3, d0 = (t & 7) * 4;
        s_wt[d0 + 0][ch] = a.x - bb.x;
        s_wt[d0 + 1][ch] = a.y - bb.y;
        s_wt[d0 + 2][ch] = a.z - bb.z;
        s_wt[d0 + 3][ch] = a.w - bb.w;
    }
    if (t < 32) s_bd[t] = fcs_b[ch0 + t] - fcs_b[C + ch0 + t];
    __syncthreads();

    // attn: 32ch x 12 (g,j) sigmoids (k = t>>5 handles p=k and p=k+8)
    {
        const int ch_l = t & 31, k = t >> 5;
        float wd[D];
        #pragma unroll
        for (int d = 0; d < D; ++d) wd[d] = s_wt[d][ch_l];
        const float bdv = s_bd[ch_l];

        {
            const int g1 = k >> 2, j = k & 3;
            float acc = bdv;
            #pragma unroll
            for (int d = 0; d < D; ++d) acc += s_z[g1][j * 32 + d] * wd[d];
            s_A[ch_l][k] = 1.0f / (1.0f + __expf(-acc));
        }
        if (k < 4) {
            const int p = k + 8;
            const int g1 = p >> 2, j = p & 3;
            float acc = bdv;
            #pragma unroll
            for (int d = 0; d < D; ++d) acc += s_z[g1][j * 32 + d] * wd[d];
            s_A[ch_l][p] = 1.0f / (1.0f + __expf(-acc));
        }
    }
    __syncthreads();

    // streaming elementwise output, plain float4 stores
    const size_t xbase = (size_t)b * (C * 256);
    const size_t obase = (size_t)b * (C * 192);
    const size_t out2_off = (size_t)BS * C * 192;
    const float* E1 = E;
    const float* E2 = E + (size_t)C * 192;

    #pragma unroll
    for (int i = 0; i < 6; ++i) {
        const int v    = t + i * 256;        // 0..1535 float4 index
        const int ch_l = v / 48;             // 0..31
        const int rem  = v - ch_l * 48;      // g1*16 + h*4 + j
        const int ch   = ch0 + ch_l;
        const int j    = rem & 3;
        const int g1   = rem >> 4;

        const float at0 = s_A[ch_l][g1 * 4 + j];
        const float at1 = 1.0f - at0;

        const size_t xofs = xbase + ch * 256 + 64 + rem * 4;
        float4 a  = *(const float4*)(x  + xofs);
        float4 c2 = *(const float4*)(x1 + xofs);
        const size_t eofs = (size_t)ch * 192 + rem * 4;
        float4 e1 = *(const float4*)(E1 + eofs);
        float4 e2 = *(const float4*)(E2 + eofs);

        float4 r1, r2;
        r1.x = at0 * a.x + e1.x;   r2.x = at1 * c2.x + e2.x;
        r1.y = at0 * a.y + e1.y;   r2.y = at1 * c2.y + e2.y;
        r1.z = at0 * a.z + e1.z;   r2.z = at1 * c2.z + e2.z;
        r1.w = at0 * a.w + e1.w;   r2.w = at1 * c2.w + e2.w;

        const size_t oofs = obase + ch * 192 + rem * 4;
        *(float4*)(out + oofs) = r1;
        *(float4*)(out + out2_off + oofs) = r2;
    }
}

extern "C" void kernel_launch(void* const* d_in, const int* in_sizes, int n_in,
                              void* d_out, int out_size, void* d_ws, size_t ws_size,
                              hipStream_t stream) {
    const float* x     = (const float*)d_in[0];
    const float* x1    = (const float*)d_in[1];
    const float* fc_w  = (const float*)d_in[2];
    const float* fc_b  = (const float*)d_in[3];
    const float* fcs_w = (const float*)d_in[4];
    const float* fcs_b = (const float*)d_in[5];
    float* out = (float*)d_out;

    float* P = (float*)d_ws;            // 3*128*4*128 = 196608 f
    float* E = P + 196608;              // 2*512*192   = 196608 f

    skatt_meanz<<<dim3(3, BS, 5), 256, 0, stream>>>(x, x1, fc_w, P, E);
    skatt_outf <<<dim3(16, BS),   256, 0, stream>>>(x, x1, E, P, fc_b, fcs_w, fcs_b, out);
}